// Round 1
// baseline (208.685 us; speedup 1.0000x reference)
//
#include <hip/hip_runtime.h>
#include <hip/hip_bf16.h>

#define TPTS 524288
#define NB 1024
#define NQ 64
#define NGF 16
#define NWW 64
#define NWF 128
#define NCLS 10

// ---------------------------------------------------------------------------
// Kernel 1: per-point weight MLP + gaussian rep + segment-sum into v[2][B][Q]
// 256 threads/block, 256 points/block. Phase 1: thread-per-point MLP.
// Phase 2: wave-per-64-points, lane = gaussian center q, register segment
// accumulation, atomic flush at segment boundaries (batch ids are sorted).
// ---------------------------------------------------------------------------
__global__ __launch_bounds__(256) void perslay_points(
    const float* __restrict__ diag0, const float* __restrict__ diag1,
    const int* __restrict__ batch0, const int* __restrict__ batch1,
    const float* __restrict__ theta,
    const float* __restrict__ Ww0, const float* __restrict__ bw0,
    const float* __restrict__ Ww1, const float* __restrict__ bw1,
    const float* __restrict__ Wwo, const float* __restrict__ bwo,
    float* __restrict__ v)
{
  const int chunksPerDiag = TPTS / 256;
  int blk = blockIdx.x;
  int dsel = (blk >= chunksPerDiag) ? 1 : 0;
  const float* diag = dsel ? diag1 : diag0;
  const int*  batch = dsel ? batch1 : batch0;
  float* vout = v + dsel * NB * NQ;
  int chunk = dsel ? (blk - chunksPerDiag) : blk;
  int ptIdx = chunk * 256 + threadIdx.x;

  float2 p = ((const float2*)diag)[ptIdx];
  int bid = batch[ptIdx];

  // ---- Phase 1: weight MLP (thread-per-point) ----
  // acc[k] accumulates h1[k] = sum_i relu(h0[i]) * Ww1[i][k] + bw1[k]
  float acc[NWW];
  #pragma unroll
  for (int k = 0; k < NWW; k++) acc[k] = bw1[k];

  for (int i = 0; i < NWW; i++) {
    // h0[i] = relu(p.x*Ww0[0][i] + p.y*Ww0[1][i] + bw0[i]); recomputed (cheap)
    float hi = fmaf(p.x, Ww0[i], fmaf(p.y, Ww0[NWW + i], bw0[i]));
    hi = fmaxf(hi, 0.0f);
    #pragma unroll
    for (int k = 0; k < NWW; k++)
      acc[k] = fmaf(hi, Ww1[i * NWW + k], acc[k]);
  }

  float z = bwo[0];
  #pragma unroll
  for (int k = 0; k < NWW; k++)
    z = fmaf(fmaxf(acc[k], 0.0f), Wwo[k], z);
  float wgt = 1.0f / (1.0f + __expf(-z));   // sigmoid

  // ---- handoff to phase 2 via LDS: (x, y, w, batch) packed in float4 ----
  __shared__ float4 pt[256];
  pt[threadIdx.x] = make_float4(p.x, p.y, wgt, __int_as_float(bid));
  __syncthreads();

  // ---- Phase 2: lane = q center; wave walks its 64 points ----
  int lane = threadIdx.x & 63;
  int base = (threadIdx.x >> 6) * 64;
  float thx = theta[2 * lane];
  float thy = theta[2 * lane + 1];
  float tt  = fmaf(thx, thx, thy * thy);

  float4 q0 = pt[base];
  int cur = __float_as_int(q0.w);
  float a2 = 0.0f;
  for (int t = 0; t < 64; t++) {
    float4 q = pt[base + t];            // uniform address -> LDS broadcast
    int b = __float_as_int(q.w);
    if (b != cur) {                     // wave-uniform branch (batch sorted)
      unsafeAtomicAdd(&vout[cur * NQ + lane], a2);
      a2 = 0.0f;
      cur = b;
    }
    float pp    = fmaf(q.x, q.x, q.y * q.y);
    float cross = fmaf(q.x, thx, q.y * thy);
    float sq    = pp + tt - 2.0f * cross;
    a2 = fmaf(q.z, __expf(-50.0f * sq), a2);   // exp(-sq/(2*0.1^2))
  }
  unsafeAtomicAdd(&vout[cur * NQ + lane], a2);
}

// ---------------------------------------------------------------------------
// Kernel 2: final MLP head. One block (128 thr) per graph.
// x = [v0[b], v1[b], gf[b]] (144) -> relu(144x128) -> relu(128x128) -> 128x10
// ---------------------------------------------------------------------------
__global__ __launch_bounds__(128) void perslay_final(
    const float* __restrict__ v, const float* __restrict__ gf,
    const float* __restrict__ Wr0, const float* __restrict__ br0,
    const float* __restrict__ Wr1, const float* __restrict__ br1,
    const float* __restrict__ Wro, const float* __restrict__ bro,
    float* __restrict__ out)
{
  __shared__ float xin[2 * NQ + NGF];
  __shared__ float h[NWF];
  int b = blockIdx.x, tid = threadIdx.x;

  if (tid < NQ) xin[tid] = v[b * NQ + tid];                       // v0
  else          xin[tid] = v[NB * NQ + b * NQ + (tid - NQ)];      // v1
  if (tid < NGF) xin[2 * NQ + tid] = gf[b * NGF + tid];
  __syncthreads();

  float a = br0[tid];
  for (int i = 0; i < 2 * NQ + NGF; i++)
    a = fmaf(xin[i], Wr0[i * NWF + tid], a);
  a = fmaxf(a, 0.0f);
  h[tid] = a;
  __syncthreads();

  float a2 = br1[tid];
  for (int i = 0; i < NWF; i++)
    a2 = fmaf(h[i], Wr1[i * NWF + tid], a2);
  a2 = fmaxf(a2, 0.0f);
  __syncthreads();                      // before reusing xin
  xin[tid] = a2;
  __syncthreads();

  if (tid < NCLS) {
    float o = bro[tid];
    for (int i = 0; i < NWF; i++)
      o = fmaf(xin[i], Wro[i * NCLS + tid], o);
    out[b * NCLS + tid] = o;
  }
}

extern "C" void kernel_launch(void* const* d_in, const int* in_sizes, int n_in,
                              void* d_out, int out_size, void* d_ws, size_t ws_size,
                              hipStream_t stream) {
  const float* diag0 = (const float*)d_in[0];
  const float* diag1 = (const float*)d_in[1];
  const float* gf    = (const float*)d_in[2];
  const float* theta = (const float*)d_in[3];
  const float* Ww0   = (const float*)d_in[4];
  const float* bw0   = (const float*)d_in[5];
  const float* Ww1   = (const float*)d_in[6];
  const float* bw1   = (const float*)d_in[7];
  const float* Wwo   = (const float*)d_in[8];
  const float* bwo   = (const float*)d_in[9];
  const float* Wr0   = (const float*)d_in[10];
  const float* br0   = (const float*)d_in[11];
  const float* Wr1   = (const float*)d_in[12];
  const float* br1   = (const float*)d_in[13];
  const float* Wro   = (const float*)d_in[14];
  const float* bro   = (const float*)d_in[15];
  const int* batch0  = (const int*)d_in[16];
  const int* batch1  = (const int*)d_in[17];

  float* v = (float*)d_ws;   // [2][B][Q] segment sums
  hipMemsetAsync(v, 0, (size_t)(2 * NB * NQ) * sizeof(float), stream);

  perslay_points<<<2 * (TPTS / 256), 256, 0, stream>>>(
      diag0, diag1, batch0, batch1, theta,
      Ww0, bw0, Ww1, bw1, Wwo, bwo, v);

  perslay_final<<<NB, 128, 0, stream>>>(
      v, gf, Wr0, br0, Wr1, br1, Wro, bro, (float*)d_out);
}